// Round 1
// 1340.519 us; speedup vs baseline: 1.0028x; 1.0028x over previous
//
#include <hip/hip_runtime.h>
#include <hip/hip_bf16.h>
#include <cstdint>
#include <cstddef>

// Problem constants (B,T,H,W,D)=(2,8,16,16,2048), E=16, I=2048
#define NTOK 4096   // N = B*T*H*W
#define NEXP 16     // E
#define DIM  2048   // D
#define IDIM 2048   // I
#define CAP  640    // 2 * ceil(N/E * 1.25)
#define SEQ  2048   // T*H*W
// token n <-> memory row (n&1)*SEQ + (n>>1)   (B=2)

typedef float v4f __attribute__((ext_vector_type(4)));
typedef short v8s __attribute__((ext_vector_type(8)));

__device__ __forceinline__ unsigned short f2b(float x) {
    union { float f; unsigned u; } c; c.f = x;
    unsigned r = c.u + 0x7FFFu + ((c.u >> 16) & 1u);
    return (unsigned short)(r >> 16);
}
__device__ __forceinline__ float b2f(unsigned short x) {
    union { unsigned u; float f; } c; c.u = ((unsigned)x) << 16;
    return c.f;
}

// async 16B global -> LDS (lds dest must be wave-uniform base; lane i lands at base + i*16B)
__device__ __forceinline__ void async16(const void* g, void* l) {
    __builtin_amdgcn_global_load_lds(
        (const __attribute__((address_space(1))) unsigned int*)g,
        (__attribute__((address_space(3))) unsigned int*)l,
        16, 0, 0);
}

// ---------------- Kernel 1: router (fp32 exact) ----------------
__global__ __launch_bounds__(256) void router_kernel(
    const float* __restrict__ hidden, const float* __restrict__ wg,
    int* __restrict__ top1, int* __restrict__ top2,
    float* __restrict__ w1, float* __restrict__ w2)
{
    int wid  = threadIdx.x >> 6;
    int lane = threadIdx.x & 63;
    int n = blockIdx.x * 4 + wid;
    int e = lane & 15;
    int chunk = lane >> 4;
    const float* tok  = hidden + ((size_t)(n & 1) * SEQ + (n >> 1)) * DIM;
    const float* wrow = wg + (size_t)e * DIM;
    float acc = 0.f;
    int d0 = chunk * (DIM / 4);
    #pragma unroll 4
    for (int d = d0; d < d0 + DIM / 4; d += 4) {
        float4 t4 = *(const float4*)(tok + d);
        float4 g4 = *(const float4*)(wrow + d);
        acc += t4.x * g4.x + t4.y * g4.y + t4.z * g4.z + t4.w * g4.w;
    }
    acc += __shfl_down(acc, 32);
    acc += __shfl_down(acc, 16);
    float v = acc;
    float v1 = v; int i1 = e;
    #pragma unroll
    for (int off = 8; off; off >>= 1) {
        float ov = __shfl_xor(v1, off);
        int   oi = __shfl_xor(i1, off);
        if (ov > v1 || (ov == v1 && oi < i1)) { v1 = ov; i1 = oi; }
    }
    float v2 = (e == i1) ? -INFINITY : v; int i2 = e;
    #pragma unroll
    for (int off = 8; off; off >>= 1) {
        float ov = __shfl_xor(v2, off);
        int   oi = __shfl_xor(i2, off);
        if (ov > v2 || (ov == v2 && oi < i2)) { v2 = ov; i2 = oi; }
    }
    if (lane == 0) {
        float e2v = expf(v2 - v1);
        float inv = 1.f / (1.f + e2v);
        top1[n] = i1; top2[n] = i2;
        w1[n] = inv;  w2[n] = e2v * inv;
    }
}

// ---------------- Kernel 2: slot scan (one wave per expert) ----------------
__global__ __launch_bounds__(1024) void slot_kernel(
    const int* __restrict__ top1, const int* __restrict__ top2,
    int* __restrict__ slot1, int* __restrict__ slot2,
    int* __restrict__ exp_tok, int* __restrict__ counts)
{
    int w = threadIdx.x >> 6;   // expert id
    int lane = threadIdx.x & 63;
    unsigned long long below = (lane == 0) ? 0ull : ((~0ull) >> (64 - lane));
    int base = 0;
    for (int c = 0; c < NTOK / 64; ++c) {
        int n = c * 64 + lane;
        bool p = (top1[n] == w);
        unsigned long long m = __ballot(p);
        if (p) {
            int s = base + __popcll(m & below);
            slot1[n] = s;
            if (s < CAP) exp_tok[w * CAP + s] = n;
        }
        base += __popcll(m);
    }
    for (int c = 0; c < NTOK / 64; ++c) {
        int n = c * 64 + lane;
        bool p = (top2[n] == w);
        unsigned long long m = __ballot(p);
        if (p) {
            int s = base + __popcll(m & below);
            slot2[n] = s;
            if (s < CAP) exp_tok[w * CAP + s] = n;
        }
        base += __popcll(m);
    }
    if (lane == 0) counts[w] = base < CAP ? base : CAP;
}

// ---------------- Kernel 3: dispatch/gather -> (E,C,D) bf16 ----------------
__global__ __launch_bounds__(256) void dispatch_kernel(
    const float* __restrict__ hidden, const int* __restrict__ exp_tok,
    const int* __restrict__ counts, unsigned short* __restrict__ disp)
{
    int s = blockIdx.x, e = blockIdx.y;
    unsigned short* dst = disp + ((size_t)e * CAP + s) * DIM + threadIdx.x * 8;
    if (s < counts[e]) {
        int n = exp_tok[e * CAP + s];
        const float* src = hidden + ((size_t)(n & 1) * SEQ + (n >> 1)) * DIM + threadIdx.x * 8;
        float4 a = *(const float4*)src;
        float4 b = *(const float4*)(src + 4);
        v8s o;
        o[0] = (short)f2b(a.x); o[1] = (short)f2b(a.y);
        o[2] = (short)f2b(a.z); o[3] = (short)f2b(a.w);
        o[4] = (short)f2b(b.x); o[5] = (short)f2b(b.y);
        o[6] = (short)f2b(b.z); o[7] = (short)f2b(b.w);
        *(v8s*)dst = o;
    } else {
        v8s z = {0, 0, 0, 0, 0, 0, 0, 0};
        *(v8s*)dst = z;
    }
}

// ---------------- GEMM tiling ----------------
// 128x128 tile, BK=64, all-bf16 MFMA operands.
// A-tiles (bf16 in memory): global_load_lds staging with XOR column-block
// swizzle done on the GLOBAL source address (LDS stays linear).
// B-tiles (fp32 weights in memory): register staging -- global_load_dwordx4,
// f2b convert in-register, ds_write_b128 directly to the swizzled LDS slot.
// LDS slot (row, cb) holds global col-block cb^(row&7); fragment b128 reads
// then hit 8 distinct bank-groups across lrow (2-way = free).
#define BM 128
#define BN 128
#define BK 64

// stage one 128x64 bf16 tile (row stride rs elems) into lds (128*64 shorts)
__device__ __forceinline__ void stage_tile(
    const unsigned short* __restrict__ gbase, int grow0, int k0, int rs,
    unsigned short* lds, int wv, int ln)
{
    int sr = ln >> 3;    // 0..7
    int cb = ln & 7;     // col-block
    #pragma unroll
    for (int p = 0; p < 4; ++p) {
        int r = p * 32 + wv * 8 + sr;
        const unsigned short* g = gbase + (size_t)(grow0 + r) * rs + k0 + ((cb ^ (r & 7)) << 3);
        async16(g, lds + (p * 32 + wv * 8) * 64);   // wave-uniform base
    }
}

// stage one 128x64 tile from FP32 source, converting to bf16 in-register.
// thread t: col-block cb=t&7 (global cols cb*8..cb*8+7), rows (t>>3)+p*32.
// global: 8 lanes cover one full 256B row -> coalesced. ds_write_b128 covers
// contiguous 1KB per wave modulo within-128B permutation -> conflict-free.
__device__ __forceinline__ void stage_tile_f32(
    const float* __restrict__ gbase, int grow0, int k0, int rs,
    unsigned short* lds, int tid)
{
    int cb = tid & 7;
    int r0 = tid >> 3;   // 0..31
    #pragma unroll
    for (int p = 0; p < 4; ++p) {
        int r = p * 32 + r0;
        const float* g = gbase + (size_t)(grow0 + r) * rs + k0 + (cb << 3);
        float4 x = *(const float4*)g;
        float4 y = *(const float4*)(g + 4);
        v8s o;
        o[0] = (short)f2b(x.x); o[1] = (short)f2b(x.y);
        o[2] = (short)f2b(x.z); o[3] = (short)f2b(x.w);
        o[4] = (short)f2b(y.x); o[5] = (short)f2b(y.y);
        o[6] = (short)f2b(y.z); o[7] = (short)f2b(y.w);
        *(v8s*)&lds[r * 64 + (((cb ^ (r & 7)) & 7) << 3)] = o;
    }
}

// XCD-chunked bijective swizzle for NB=1280 blocks (8 XCDs x 160).
// Within a chunk m varies fastest -> the 5 m-blocks sharing a B panel run
// back-to-back on one XCD (B fetched from HBM once); each XCD owns 2 experts.
__device__ __forceinline__ void grid_decomp(int bid, int& mi, int& ni, int& e) {
    int swz = (bid & 7) * 160 + (bid >> 3);
    mi = swz % 5;
    int t = swz / 5;
    ni = t & 15;
    e  = t >> 4;
}

// Kernel 4: h = silu(disp @ gp^T) * (disp @ up^T), per expert. Out bf16 (E,C,I)
__global__ __launch_bounds__(256) void gateup_kernel(
    const unsigned short* __restrict__ disp, const float* __restrict__ gp,
    const float* __restrict__ up, const int* __restrict__ counts,
    unsigned short* __restrict__ hbuf)
{
    __shared__ unsigned short As[BM * BK];
    __shared__ unsigned short Bgs[BN * BK];
    __shared__ unsigned short Bus[BN * BK];
    int mi, ni, e;
    grid_decomp(blockIdx.x, mi, ni, e);
    int m0 = mi * BM;
    if (m0 >= counts[e]) return;   // rows beyond count never read by combine
    int n0 = ni * BN;
    int tid = threadIdx.x;
    int wv = tid >> 6, ln = tid & 63;
    int wm = wv & 1, wn = wv >> 1;
    int lrow = ln & 15, quad = ln >> 4;
    int sw = lrow & 7;

    const unsigned short* Ab = disp + (size_t)e * CAP * DIM;
    const float* Gb = gp + (size_t)e * IDIM * DIM;
    const float* Ub = up + (size_t)e * IDIM * DIM;

    int arow[4], brow[4];
    #pragma unroll
    for (int i = 0; i < 4; ++i) {
        arow[i] = (wm * 64 + i * 16 + lrow) * 64;
        brow[i] = (wn * 64 + i * 16 + lrow) * 64;
    }

    v4f accg[4][4], accu[4][4];
    #pragma unroll
    for (int i = 0; i < 4; ++i)
        #pragma unroll
        for (int j = 0; j < 4; ++j) { accg[i][j] = (v4f)0.f; accu[i][j] = (v4f)0.f; }

    for (int k0 = 0; k0 < DIM; k0 += BK) {
        stage_tile(Ab, m0, k0, DIM, As, wv, ln);          // async, in flight
        stage_tile_f32(Gb, n0, k0, DIM, Bgs, tid);        // reg-staged + convert
        stage_tile_f32(Ub, n0, k0, DIM, Bus, tid);
        __syncthreads();
        #pragma unroll
        for (int ks = 0; ks < BK; ks += 32) {
            int cq = ks >> 3;
            v8s a[4], bg[4], bu[4];
            #pragma unroll
            for (int i = 0; i < 4; ++i)
                a[i] = *(const v8s*)&As[arow[i] + (((cq + quad) ^ sw) << 3)];
            #pragma unroll
            for (int j = 0; j < 4; ++j) {
                bg[j] = *(const v8s*)&Bgs[brow[j] + (((cq + quad) ^ sw) << 3)];
                bu[j] = *(const v8s*)&Bus[brow[j] + (((cq + quad) ^ sw) << 3)];
            }
            #pragma unroll
            for (int i = 0; i < 4; ++i)
                #pragma unroll
                for (int j = 0; j < 4; ++j) {
                    accg[i][j] = __builtin_amdgcn_mfma_f32_16x16x32_bf16(a[i], bg[j], accg[i][j], 0, 0, 0);
                    accu[i][j] = __builtin_amdgcn_mfma_f32_16x16x32_bf16(a[i], bu[j], accu[i][j], 0, 0, 0);
                }
        }
        __syncthreads();
    }
    unsigned short* hb = hbuf + (size_t)e * CAP * IDIM;
    #pragma unroll
    for (int i = 0; i < 4; ++i)
        #pragma unroll
        for (int j = 0; j < 4; ++j) {
            int row = m0 + wm * 64 + i * 16 + quad * 4;
            int col = n0 + wn * 64 + j * 16 + lrow;
            #pragma unroll
            for (int rg = 0; rg < 4; ++rg) {
                float g = accg[i][j][rg], u = accu[i][j][rg];
                float hv = (g / (1.f + __expf(-g))) * u;
                hb[(size_t)(row + rg) * IDIM + col] = f2b(hv);
            }
        }
}

// Kernel 5: expert_out = h @ dp^T per expert. Out bf16 (E,C,D)
__global__ __launch_bounds__(256) void down_kernel(
    const unsigned short* __restrict__ hbuf, const float* __restrict__ dp,
    const int* __restrict__ counts, unsigned short* __restrict__ eo)
{
    __shared__ unsigned short As[BM * BK];
    __shared__ unsigned short Bs[BN * BK];
    int mi, ni, e;
    grid_decomp(blockIdx.x, mi, ni, e);
    int m0 = mi * BM;
    if (m0 >= counts[e]) return;
    int n0 = ni * BN;
    int tid = threadIdx.x;
    int wv = tid >> 6, ln = tid & 63;
    int wm = wv & 1, wn = wv >> 1;
    int lrow = ln & 15, quad = ln >> 4;
    int sw = lrow & 7;

    const unsigned short* Ab = hbuf + (size_t)e * CAP * IDIM;
    const float* Db = dp + (size_t)e * DIM * IDIM;

    int arow[4], brow[4];
    #pragma unroll
    for (int i = 0; i < 4; ++i) {
        arow[i] = (wm * 64 + i * 16 + lrow) * 64;
        brow[i] = (wn * 64 + i * 16 + lrow) * 64;
    }

    v4f acc[4][4];
    #pragma unroll
    for (int i = 0; i < 4; ++i)
        #pragma unroll
        for (int j = 0; j < 4; ++j) acc[i][j] = (v4f)0.f;

    for (int k0 = 0; k0 < IDIM; k0 += BK) {
        stage_tile(Ab, m0, k0, IDIM, As, wv, ln);
        stage_tile_f32(Db, n0, k0, IDIM, Bs, tid);
        __syncthreads();
        #pragma unroll
        for (int ks = 0; ks < BK; ks += 32) {
            int cq = ks >> 3;
            v8s a[4], b[4];
            #pragma unroll
            for (int i = 0; i < 4; ++i)
                a[i] = *(const v8s*)&As[arow[i] + (((cq + quad) ^ sw) << 3)];
            #pragma unroll
            for (int j = 0; j < 4; ++j)
                b[j] = *(const v8s*)&Bs[brow[j] + (((cq + quad) ^ sw) << 3)];
            #pragma unroll
            for (int i = 0; i < 4; ++i)
                #pragma unroll
                for (int j = 0; j < 4; ++j)
                    acc[i][j] = __builtin_amdgcn_mfma_f32_16x16x32_bf16(a[i], b[j], acc[i][j], 0, 0, 0);
        }
        __syncthreads();
    }
    unsigned short* ob = eo + (size_t)e * CAP * DIM;
    #pragma unroll
    for (int i = 0; i < 4; ++i)
        #pragma unroll
        for (int j = 0; j < 4; ++j) {
            int row = m0 + wm * 64 + i * 16 + quad * 4;
            int col = n0 + wn * 64 + j * 16 + lrow;
            #pragma unroll
            for (int rg = 0; rg < 4; ++rg)
                ob[(size_t)(row + rg) * DIM + col] = f2b(acc[i][j][rg]);
        }
}

// ---------------- Kernel 6: combine ----------------
__global__ __launch_bounds__(256) void combine_kernel(
    const unsigned short* __restrict__ eo,
    const int* __restrict__ top1, const int* __restrict__ top2,
    const int* __restrict__ slot1, const int* __restrict__ slot2,
    const float* __restrict__ w1, const float* __restrict__ w2,
    float* __restrict__ out)
{
    int n = blockIdx.x;
    int d = threadIdx.x * 8;
    float acc[8];
    #pragma unroll
    for (int i = 0; i < 8; ++i) acc[i] = 0.f;
    int s1 = slot1[n], s2 = slot2[n];
    if (s1 < CAP) {
        const unsigned short* p = eo + ((size_t)top1[n] * CAP + s1) * DIM + d;
        float w = w1[n];
        v8s v = *(const v8s*)p;
        #pragma unroll
        for (int i = 0; i < 8; ++i) acc[i] += w * b2f((unsigned short)v[i]);
    }
    if (s2 < CAP) {
        const unsigned short* p = eo + ((size_t)top2[n] * CAP + s2) * DIM + d;
        float w = w2[n];
        v8s v = *(const v8s*)p;
        #pragma unroll
        for (int i = 0; i < 8; ++i) acc[i] += w * b2f((unsigned short)v[i]);
    }
    float* o = out + ((size_t)(n & 1) * SEQ + (n >> 1)) * DIM + d;
    float4 o0 = {acc[0], acc[1], acc[2], acc[3]};
    float4 o1 = {acc[4], acc[5], acc[6], acc[7]};
    *(float4*)o = o0;
    *(float4*)(o + 4) = o1;
}

extern "C" void kernel_launch(void* const* d_in, const int* in_sizes, int n_in,
                              void* d_out, int out_size, void* d_ws, size_t ws_size,
                              hipStream_t stream) {
    const float* hidden = (const float*)d_in[0];
    const float* wg     = (const float*)d_in[1];
    const float* gp     = (const float*)d_in[2];
    const float* up     = (const float*)d_in[3];
    const float* dp     = (const float*)d_in[4];
    float* out = (float*)d_out;
    char* ws = (char*)d_ws;

    // workspace layout
    int*   top1    = (int*)(ws + 0);
    int*   top2    = (int*)(ws + 16384);
    float* w1      = (float*)(ws + 32768);
    float* w2      = (float*)(ws + 49152);
    int*   slot1   = (int*)(ws + 65536);
    int*   slot2   = (int*)(ws + 81920);
    int*   counts  = (int*)(ws + 98304);
    int*   exp_tok = (int*)(ws + 98560);
    unsigned short* disp = (unsigned short*)(ws + 262144);                    // 41,943,040 B
    unsigned short* hbuf = (unsigned short*)(ws + 262144 + 41943040ull);      // 41,943,040 B
    unsigned short* eo   = (unsigned short*)(ws + 262144 + 2ull*41943040ull); // 41,943,040 B
    // total ~126 MB (weight-conversion buffers eliminated)

    const int NB = (CAP / BM) * (IDIM / BN) * NEXP;   // 1280, = 8 XCDs * 160

    router_kernel<<<NTOK / 4, 256, 0, stream>>>(hidden, wg, top1, top2, w1, w2);
    slot_kernel<<<1, 1024, 0, stream>>>(top1, top2, slot1, slot2, exp_tok, counts);
    dispatch_kernel<<<dim3(CAP, NEXP), 256, 0, stream>>>(hidden, exp_tok, counts, disp);
    gateup_kernel<<<NB, 256, 0, stream>>>(disp, gp, up, counts, hbuf);
    down_kernel<<<NB, 256, 0, stream>>>(hbuf, dp, counts, eo);
    combine_kernel<<<NTOK, 256, 0, stream>>>(eo, top1, top2, slot1, slot2, w1, w2, out);
}

// Round 2
// 1096.972 us; speedup vs baseline: 1.2254x; 1.2220x over previous
//
#include <hip/hip_runtime.h>
#include <hip/hip_bf16.h>
#include <cstdint>
#include <cstddef>

// Problem constants (B,T,H,W,D)=(2,8,16,16,2048), E=16, I=2048
#define NTOK 4096   // N = B*T*H*W
#define NEXP 16     // E
#define DIM  2048   // D
#define IDIM 2048   // I
#define CAP  640    // 2 * ceil(N/E * 1.25)
#define SEQ  2048   // T*H*W
// token n <-> memory row (n&1)*SEQ + (n>>1)   (B=2)

typedef float v4f __attribute__((ext_vector_type(4)));
typedef short v8s __attribute__((ext_vector_type(8)));

__device__ __forceinline__ unsigned short f2b(float x) {
    union { float f; unsigned u; } c; c.f = x;
    unsigned r = c.u + 0x7FFFu + ((c.u >> 16) & 1u);
    return (unsigned short)(r >> 16);
}
__device__ __forceinline__ float b2f(unsigned short x) {
    union { unsigned u; float f; } c; c.u = ((unsigned)x) << 16;
    return c.f;
}

// async 16B global -> LDS (lds dest must be wave-uniform base; lane i lands at base + i*16B)
__device__ __forceinline__ void async16(const void* g, void* l) {
    __builtin_amdgcn_global_load_lds(
        (const __attribute__((address_space(1))) unsigned int*)g,
        (__attribute__((address_space(3))) unsigned int*)l,
        16, 0, 0);
}

// ---------------- Kernel 1: router (fp32 exact) ----------------
__global__ __launch_bounds__(256) void router_kernel(
    const float* __restrict__ hidden, const float* __restrict__ wg,
    int* __restrict__ top1, int* __restrict__ top2,
    float* __restrict__ w1, float* __restrict__ w2)
{
    int wid  = threadIdx.x >> 6;
    int lane = threadIdx.x & 63;
    int n = blockIdx.x * 4 + wid;
    int e = lane & 15;
    int chunk = lane >> 4;
    const float* tok  = hidden + ((size_t)(n & 1) * SEQ + (n >> 1)) * DIM;
    const float* wrow = wg + (size_t)e * DIM;
    float acc = 0.f;
    int d0 = chunk * (DIM / 4);
    #pragma unroll 4
    for (int d = d0; d < d0 + DIM / 4; d += 4) {
        float4 t4 = *(const float4*)(tok + d);
        float4 g4 = *(const float4*)(wrow + d);
        acc += t4.x * g4.x + t4.y * g4.y + t4.z * g4.z + t4.w * g4.w;
    }
    acc += __shfl_down(acc, 32);
    acc += __shfl_down(acc, 16);
    float v = acc;
    float v1 = v; int i1 = e;
    #pragma unroll
    for (int off = 8; off; off >>= 1) {
        float ov = __shfl_xor(v1, off);
        int   oi = __shfl_xor(i1, off);
        if (ov > v1 || (ov == v1 && oi < i1)) { v1 = ov; i1 = oi; }
    }
    float v2 = (e == i1) ? -INFINITY : v; int i2 = e;
    #pragma unroll
    for (int off = 8; off; off >>= 1) {
        float ov = __shfl_xor(v2, off);
        int   oi = __shfl_xor(i2, off);
        if (ov > v2 || (ov == v2 && oi < i2)) { v2 = ov; i2 = oi; }
    }
    if (lane == 0) {
        float e2v = expf(v2 - v1);
        float inv = 1.f / (1.f + e2v);
        top1[n] = i1; top2[n] = i2;
        w1[n] = inv;  w2[n] = e2v * inv;
    }
}

// ---------------- Kernel 2: slot scan (one wave per expert) ----------------
__global__ __launch_bounds__(1024) void slot_kernel(
    const int* __restrict__ top1, const int* __restrict__ top2,
    int* __restrict__ slot1, int* __restrict__ slot2,
    int* __restrict__ exp_tok, int* __restrict__ counts)
{
    int w = threadIdx.x >> 6;   // expert id
    int lane = threadIdx.x & 63;
    unsigned long long below = (lane == 0) ? 0ull : ((~0ull) >> (64 - lane));
    int base = 0;
    for (int c = 0; c < NTOK / 64; ++c) {
        int n = c * 64 + lane;
        bool p = (top1[n] == w);
        unsigned long long m = __ballot(p);
        if (p) {
            int s = base + __popcll(m & below);
            slot1[n] = s;
            if (s < CAP) exp_tok[w * CAP + s] = n;
        }
        base += __popcll(m);
    }
    for (int c = 0; c < NTOK / 64; ++c) {
        int n = c * 64 + lane;
        bool p = (top2[n] == w);
        unsigned long long m = __ballot(p);
        if (p) {
            int s = base + __popcll(m & below);
            slot2[n] = s;
            if (s < CAP) exp_tok[w * CAP + s] = n;
        }
        base += __popcll(m);
    }
    if (lane == 0) counts[w] = base < CAP ? base : CAP;
}

// ---------------- Kernel 3: dispatch/gather -> (E,C,D) bf16 ----------------
__global__ __launch_bounds__(256) void dispatch_kernel(
    const float* __restrict__ hidden, const int* __restrict__ exp_tok,
    const int* __restrict__ counts, unsigned short* __restrict__ disp)
{
    int s = blockIdx.x, e = blockIdx.y;
    unsigned short* dst = disp + ((size_t)e * CAP + s) * DIM + threadIdx.x * 8;
    if (s < counts[e]) {
        int n = exp_tok[e * CAP + s];
        const float* src = hidden + ((size_t)(n & 1) * SEQ + (n >> 1)) * DIM + threadIdx.x * 8;
        float4 a = *(const float4*)src;
        float4 b = *(const float4*)(src + 4);
        v8s o;
        o[0] = (short)f2b(a.x); o[1] = (short)f2b(a.y);
        o[2] = (short)f2b(a.z); o[3] = (short)f2b(a.w);
        o[4] = (short)f2b(b.x); o[5] = (short)f2b(b.y);
        o[6] = (short)f2b(b.z); o[7] = (short)f2b(b.w);
        *(v8s*)dst = o;
    } else {
        v8s z = {0, 0, 0, 0, 0, 0, 0, 0};
        *(v8s*)dst = z;
    }
}

// ---------------- GEMM tiling ----------------
// 128x128 tile, BK=64, bf16 MFMA operands.
// A-tiles (bf16 in memory): global_load_lds (async), DOUBLE-BUFFERED, issued
//   during the compute phase of the previous K-step.
// B-tiles (fp32 weights): software-pipelined register staging (T14):
//   loads for tile k+1 are issued right after the pre-compute barrier of tile
//   k (in flight across the whole MFMA phase), converted to bf16 and
//   ds_written at the top of iteration k+1. No latency on the critical path.
// LDS slot (row, cb) holds global col-block cb^(row&7) (XOR swizzle);
// fragment b128 reads hit 8 distinct bank-groups across lrow (2-way = free).
#define BM 128
#define BN 128
#define BK 64

// stage one 128x64 bf16 tile (row stride rs elems) into lds (128*64 shorts)
__device__ __forceinline__ void stage_tile(
    const unsigned short* __restrict__ gbase, int grow0, int k0, int rs,
    unsigned short* lds, int wv, int ln)
{
    int sr = ln >> 3;    // 0..7
    int cb = ln & 7;     // col-block
    #pragma unroll
    for (int p = 0; p < 4; ++p) {
        int r = p * 32 + wv * 8 + sr;
        const unsigned short* g = gbase + (size_t)(grow0 + r) * rs + k0 + ((cb ^ (r & 7)) << 3);
        async16(g, lds + (p * 32 + wv * 8) * 64);   // wave-uniform base
    }
}

// issue fp32 loads for one 128x64 tile into registers (8 x float4 / thread)
__device__ __forceinline__ void issue_b(
    const float* __restrict__ gbase, int grow0, int k0, int rs,
    float4 (&regs)[8], int tid)
{
    int cb = tid & 7;
    int r0 = tid >> 3;   // 0..31
    #pragma unroll
    for (int p = 0; p < 4; ++p) {
        const float* g = gbase + (size_t)(grow0 + p * 32 + r0) * rs + k0 + (cb << 3);
        regs[2 * p]     = *(const float4*)g;
        regs[2 * p + 1] = *(const float4*)(g + 4);
    }
}

// convert staged fp32 regs -> bf16, write to swizzled LDS slots
__device__ __forceinline__ void write_b(
    const float4 (&regs)[8], unsigned short* lds, int tid)
{
    int cb = tid & 7;
    int r0 = tid >> 3;
    #pragma unroll
    for (int p = 0; p < 4; ++p) {
        int r = p * 32 + r0;
        float4 x = regs[2 * p], y = regs[2 * p + 1];
        v8s o;
        o[0] = (short)f2b(x.x); o[1] = (short)f2b(x.y);
        o[2] = (short)f2b(x.z); o[3] = (short)f2b(x.w);
        o[4] = (short)f2b(y.x); o[5] = (short)f2b(y.y);
        o[6] = (short)f2b(y.z); o[7] = (short)f2b(y.w);
        *(v8s*)&lds[r * 64 + ((cb ^ (r & 7)) << 3)] = o;
    }
}

// XCD-chunked bijective swizzle for NB=1280 blocks (8 XCDs x 160).
// Within a chunk m varies fastest -> the 5 m-blocks sharing a B panel run
// back-to-back on one XCD (B fetched from HBM once); each XCD owns 2 experts.
__device__ __forceinline__ void grid_decomp(int bid, int& mi, int& ni, int& e) {
    int swz = (bid & 7) * 160 + (bid >> 3);
    mi = swz % 5;
    int t = swz / 5;
    ni = t & 15;
    e  = t >> 4;
}

// Kernel 4: h = silu(disp @ gp^T) * (disp @ up^T), per expert. Out bf16 (E,C,I)
__global__ __launch_bounds__(256, 2) void gateup_kernel(
    const unsigned short* __restrict__ disp, const float* __restrict__ gp,
    const float* __restrict__ up, const int* __restrict__ counts,
    unsigned short* __restrict__ hbuf)
{
    __shared__ unsigned short As[2][BM * BK];
    __shared__ unsigned short Bgs[BN * BK];
    __shared__ unsigned short Bus[BN * BK];
    int mi, ni, e;
    grid_decomp(blockIdx.x, mi, ni, e);
    int m0 = mi * BM;
    if (m0 >= counts[e]) return;   // rows beyond count never read by combine
    int n0 = ni * BN;
    int tid = threadIdx.x;
    int wv = tid >> 6, ln = tid & 63;
    int wm = wv & 1, wn = wv >> 1;
    int lrow = ln & 15, quad = ln >> 4;
    int sw = lrow & 7;

    const unsigned short* Ab = disp + (size_t)e * CAP * DIM;
    const float* Gb = gp + (size_t)e * IDIM * DIM;
    const float* Ub = up + (size_t)e * IDIM * DIM;

    int arow[4], brow[4];
    #pragma unroll
    for (int i = 0; i < 4; ++i) {
        arow[i] = (wm * 64 + i * 16 + lrow) * 64;
        brow[i] = (wn * 64 + i * 16 + lrow) * 64;
    }

    v4f accg[4][4], accu[4][4];
    #pragma unroll
    for (int i = 0; i < 4; ++i)
        #pragma unroll
        for (int j = 0; j < 4; ++j) { accg[i][j] = (v4f)0.f; accu[i][j] = (v4f)0.f; }

    float4 rg[8], ru[8];
    // prologue: tile 0 in flight
    stage_tile(Ab, m0, 0, DIM, As[0], wv, ln);
    issue_b(Gb, n0, 0, DIM, rg, tid);
    issue_b(Ub, n0, 0, DIM, ru, tid);

    for (int k0 = 0; k0 < DIM; k0 += BK) {
        int cur = (k0 >> 6) & 1;
        __syncthreads();              // post-compute(k-1): drains in-flight tile k
        write_b(rg, Bgs, tid);        // convert + ds_write (regs already landed)
        write_b(ru, Bus, tid);
        __syncthreads();              // LDS (A[cur], Bg, Bu) visible to all waves
        int kn = k0 + BK;
        if (kn < DIM) {               // issue tile k+1: in flight during compute
            stage_tile(Ab, m0, kn, DIM, As[cur ^ 1], wv, ln);
            issue_b(Gb, n0, kn, DIM, rg, tid);
            issue_b(Ub, n0, kn, DIM, ru, tid);
        }
        #pragma unroll
        for (int ks = 0; ks < BK; ks += 32) {
            int cq = ks >> 3;
            v8s a[4];
            #pragma unroll
            for (int i = 0; i < 4; ++i)
                a[i] = *(const v8s*)&As[cur][arow[i] + (((cq + quad) ^ sw) << 3)];
            #pragma unroll
            for (int j = 0; j < 4; ++j) {
                v8s bg = *(const v8s*)&Bgs[brow[j] + (((cq + quad) ^ sw) << 3)];
                v8s bu = *(const v8s*)&Bus[brow[j] + (((cq + quad) ^ sw) << 3)];
                #pragma unroll
                for (int i = 0; i < 4; ++i) {
                    accg[i][j] = __builtin_amdgcn_mfma_f32_16x16x32_bf16(a[i], bg, accg[i][j], 0, 0, 0);
                    accu[i][j] = __builtin_amdgcn_mfma_f32_16x16x32_bf16(a[i], bu, accu[i][j], 0, 0, 0);
                }
            }
        }
    }
    unsigned short* hb = hbuf + (size_t)e * CAP * IDIM;
    #pragma unroll
    for (int i = 0; i < 4; ++i)
        #pragma unroll
        for (int j = 0; j < 4; ++j) {
            int row = m0 + wm * 64 + i * 16 + quad * 4;
            int col = n0 + wn * 64 + j * 16 + lrow;
            #pragma unroll
            for (int rg_ = 0; rg_ < 4; ++rg_) {
                float g = accg[i][j][rg_], u = accu[i][j][rg_];
                float hv = (g / (1.f + __expf(-g))) * u;
                hb[(size_t)(row + rg_) * IDIM + col] = f2b(hv);
            }
        }
}

// Kernel 5: expert_out = h @ dp^T per expert. Out bf16 (E,C,D)
__global__ __launch_bounds__(256, 2) void down_kernel(
    const unsigned short* __restrict__ hbuf, const float* __restrict__ dp,
    const int* __restrict__ counts, unsigned short* __restrict__ eo)
{
    __shared__ unsigned short As[2][BM * BK];
    __shared__ unsigned short Bs[BN * BK];
    int mi, ni, e;
    grid_decomp(blockIdx.x, mi, ni, e);
    int m0 = mi * BM;
    if (m0 >= counts[e]) return;
    int n0 = ni * BN;
    int tid = threadIdx.x;
    int wv = tid >> 6, ln = tid & 63;
    int wm = wv & 1, wn = wv >> 1;
    int lrow = ln & 15, quad = ln >> 4;
    int sw = lrow & 7;

    const unsigned short* Ab = hbuf + (size_t)e * CAP * IDIM;
    const float* Db = dp + (size_t)e * DIM * IDIM;

    int arow[4], brow[4];
    #pragma unroll
    for (int i = 0; i < 4; ++i) {
        arow[i] = (wm * 64 + i * 16 + lrow) * 64;
        brow[i] = (wn * 64 + i * 16 + lrow) * 64;
    }

    v4f acc[4][4];
    #pragma unroll
    for (int i = 0; i < 4; ++i)
        #pragma unroll
        for (int j = 0; j < 4; ++j) acc[i][j] = (v4f)0.f;

    float4 rb[8];
    stage_tile(Ab, m0, 0, IDIM, As[0], wv, ln);
    issue_b(Db, n0, 0, IDIM, rb, tid);

    for (int k0 = 0; k0 < IDIM; k0 += BK) {
        int cur = (k0 >> 6) & 1;
        __syncthreads();
        write_b(rb, Bs, tid);
        __syncthreads();
        int kn = k0 + BK;
        if (kn < IDIM) {
            stage_tile(Ab, m0, kn, IDIM, As[cur ^ 1], wv, ln);
            issue_b(Db, n0, kn, IDIM, rb, tid);
        }
        #pragma unroll
        for (int ks = 0; ks < BK; ks += 32) {
            int cq = ks >> 3;
            v8s a[4];
            #pragma unroll
            for (int i = 0; i < 4; ++i)
                a[i] = *(const v8s*)&As[cur][arow[i] + (((cq + quad) ^ sw) << 3)];
            #pragma unroll
            for (int j = 0; j < 4; ++j) {
                v8s b = *(const v8s*)&Bs[brow[j] + (((cq + quad) ^ sw) << 3)];
                #pragma unroll
                for (int i = 0; i < 4; ++i)
                    acc[i][j] = __builtin_amdgcn_mfma_f32_16x16x32_bf16(a[i], b, acc[i][j], 0, 0, 0);
            }
        }
    }
    unsigned short* ob = eo + (size_t)e * CAP * DIM;
    #pragma unroll
    for (int i = 0; i < 4; ++i)
        #pragma unroll
        for (int j = 0; j < 4; ++j) {
            int row = m0 + wm * 64 + i * 16 + quad * 4;
            int col = n0 + wn * 64 + j * 16 + lrow;
            #pragma unroll
            for (int rg_ = 0; rg_ < 4; ++rg_)
                ob[(size_t)(row + rg_) * DIM + col] = f2b(acc[i][j][rg_]);
        }
}

// ---------------- Kernel 6: combine ----------------
__global__ __launch_bounds__(256) void combine_kernel(
    const unsigned short* __restrict__ eo,
    const int* __restrict__ top1, const int* __restrict__ top2,
    const int* __restrict__ slot1, const int* __restrict__ slot2,
    const float* __restrict__ w1, const float* __restrict__ w2,
    float* __restrict__ out)
{
    int n = blockIdx.x;
    int d = threadIdx.x * 8;
    float acc[8];
    #pragma unroll
    for (int i = 0; i < 8; ++i) acc[i] = 0.f;
    int s1 = slot1[n], s2 = slot2[n];
    if (s1 < CAP) {
        const unsigned short* p = eo + ((size_t)top1[n] * CAP + s1) * DIM + d;
        float w = w1[n];
        v8s v = *(const v8s*)p;
        #pragma unroll
        for (int i = 0; i < 8; ++i) acc[i] += w * b2f((unsigned short)v[i]);
    }
    if (s2 < CAP) {
        const unsigned short* p = eo + ((size_t)top2[n] * CAP + s2) * DIM + d;
        float w = w2[n];
        v8s v = *(const v8s*)p;
        #pragma unroll
        for (int i = 0; i < 8; ++i) acc[i] += w * b2f((unsigned short)v[i]);
    }
    float* o = out + ((size_t)(n & 1) * SEQ + (n >> 1)) * DIM + d;
    float4 o0 = {acc[0], acc[1], acc[2], acc[3]};
    float4 o1 = {acc[4], acc[5], acc[6], acc[7]};
    *(float4*)o = o0;
    *(float4*)(o + 4) = o1;
}

extern "C" void kernel_launch(void* const* d_in, const int* in_sizes, int n_in,
                              void* d_out, int out_size, void* d_ws, size_t ws_size,
                              hipStream_t stream) {
    const float* hidden = (const float*)d_in[0];
    const float* wg     = (const float*)d_in[1];
    const float* gp     = (const float*)d_in[2];
    const float* up     = (const float*)d_in[3];
    const float* dp     = (const float*)d_in[4];
    float* out = (float*)d_out;
    char* ws = (char*)d_ws;

    // workspace layout
    int*   top1    = (int*)(ws + 0);
    int*   top2    = (int*)(ws + 16384);
    float* w1      = (float*)(ws + 32768);
    float* w2      = (float*)(ws + 49152);
    int*   slot1   = (int*)(ws + 65536);
    int*   slot2   = (int*)(ws + 81920);
    int*   counts  = (int*)(ws + 98304);
    int*   exp_tok = (int*)(ws + 98560);
    unsigned short* disp = (unsigned short*)(ws + 262144);                    // 41,943,040 B
    unsigned short* hbuf = (unsigned short*)(ws + 262144 + 41943040ull);      // 41,943,040 B
    unsigned short* eo   = (unsigned short*)(ws + 262144 + 2ull*41943040ull); // 41,943,040 B
    // total ~126 MB

    const int NB = (CAP / BM) * (IDIM / BN) * NEXP;   // 1280, = 8 XCDs * 160

    router_kernel<<<NTOK / 4, 256, 0, stream>>>(hidden, wg, top1, top2, w1, w2);
    slot_kernel<<<1, 1024, 0, stream>>>(top1, top2, slot1, slot2, exp_tok, counts);
    dispatch_kernel<<<dim3(CAP, NEXP), 256, 0, stream>>>(hidden, exp_tok, counts, disp);
    gateup_kernel<<<NB, 256, 0, stream>>>(disp, gp, up, counts, hbuf);
    down_kernel<<<NB, 256, 0, stream>>>(hbuf, dp, counts, eo);
    combine_kernel<<<NTOK, 256, 0, stream>>>(eo, top1, top2, slot1, slot2, w1, w2, out);
}

// Round 3
// 1047.722 us; speedup vs baseline: 1.2830x; 1.0470x over previous
//
#include <hip/hip_runtime.h>
#include <hip/hip_bf16.h>
#include <cstdint>
#include <cstddef>

// Problem constants (B,T,H,W,D)=(2,8,16,16,2048), E=16, I=2048
#define NTOK 4096   // N = B*T*H*W
#define NEXP 16     // E
#define DIM  2048   // D
#define IDIM 2048   // I
#define CAP  640    // 2 * ceil(N/E * 1.25)
#define SEQ  2048   // T*H*W
// token n <-> memory row (n&1)*SEQ + (n>>1)   (B=2)

typedef float v4f __attribute__((ext_vector_type(4)));
typedef short v8s __attribute__((ext_vector_type(8)));

__device__ __forceinline__ unsigned short f2b(float x) {
    union { float f; unsigned u; } c; c.f = x;
    unsigned r = c.u + 0x7FFFu + ((c.u >> 16) & 1u);
    return (unsigned short)(r >> 16);
}
__device__ __forceinline__ float b2f(unsigned short x) {
    union { unsigned u; float f; } c; c.u = ((unsigned)x) << 16;
    return c.f;
}

// async 16B global -> LDS (lds dest must be wave-uniform base; lane i lands at base + i*16B)
__device__ __forceinline__ void async16(const void* g, void* l) {
    __builtin_amdgcn_global_load_lds(
        (const __attribute__((address_space(1))) unsigned int*)g,
        (__attribute__((address_space(3))) unsigned int*)l,
        16, 0, 0);
}

// ---------------- Kernel 1: router (fp32 exact) ----------------
__global__ __launch_bounds__(256) void router_kernel(
    const float* __restrict__ hidden, const float* __restrict__ wg,
    int* __restrict__ top1, int* __restrict__ top2,
    float* __restrict__ w1, float* __restrict__ w2)
{
    int wid  = threadIdx.x >> 6;
    int lane = threadIdx.x & 63;
    int n = blockIdx.x * 4 + wid;
    int e = lane & 15;
    int chunk = lane >> 4;
    const float* tok  = hidden + ((size_t)(n & 1) * SEQ + (n >> 1)) * DIM;
    const float* wrow = wg + (size_t)e * DIM;
    float acc = 0.f;
    int d0 = chunk * (DIM / 4);
    #pragma unroll 4
    for (int d = d0; d < d0 + DIM / 4; d += 4) {
        float4 t4 = *(const float4*)(tok + d);
        float4 g4 = *(const float4*)(wrow + d);
        acc += t4.x * g4.x + t4.y * g4.y + t4.z * g4.z + t4.w * g4.w;
    }
    acc += __shfl_down(acc, 32);
    acc += __shfl_down(acc, 16);
    float v = acc;
    float v1 = v; int i1 = e;
    #pragma unroll
    for (int off = 8; off; off >>= 1) {
        float ov = __shfl_xor(v1, off);
        int   oi = __shfl_xor(i1, off);
        if (ov > v1 || (ov == v1 && oi < i1)) { v1 = ov; i1 = oi; }
    }
    float v2 = (e == i1) ? -INFINITY : v; int i2 = e;
    #pragma unroll
    for (int off = 8; off; off >>= 1) {
        float ov = __shfl_xor(v2, off);
        int   oi = __shfl_xor(i2, off);
        if (ov > v2 || (ov == v2 && oi < i2)) { v2 = ov; i2 = oi; }
    }
    if (lane == 0) {
        float e2v = expf(v2 - v1);
        float inv = 1.f / (1.f + e2v);
        top1[n] = i1; top2[n] = i2;
        w1[n] = inv;  w2[n] = e2v * inv;
    }
}

// ---------------- Kernel 2: slot scan (one wave per expert) ----------------
__global__ __launch_bounds__(1024) void slot_kernel(
    const int* __restrict__ top1, const int* __restrict__ top2,
    int* __restrict__ slot1, int* __restrict__ slot2,
    int* __restrict__ exp_tok, int* __restrict__ counts)
{
    int w = threadIdx.x >> 6;   // expert id
    int lane = threadIdx.x & 63;
    unsigned long long below = (lane == 0) ? 0ull : ((~0ull) >> (64 - lane));
    int base = 0;
    for (int c = 0; c < NTOK / 64; ++c) {
        int n = c * 64 + lane;
        bool p = (top1[n] == w);
        unsigned long long m = __ballot(p);
        if (p) {
            int s = base + __popcll(m & below);
            slot1[n] = s;
            if (s < CAP) exp_tok[w * CAP + s] = n;
        }
        base += __popcll(m);
    }
    for (int c = 0; c < NTOK / 64; ++c) {
        int n = c * 64 + lane;
        bool p = (top2[n] == w);
        unsigned long long m = __ballot(p);
        if (p) {
            int s = base + __popcll(m & below);
            slot2[n] = s;
            if (s < CAP) exp_tok[w * CAP + s] = n;
        }
        base += __popcll(m);
    }
    if (lane == 0) counts[w] = base < CAP ? base : CAP;
}

// ---------------- Kernel 3: dispatch/gather -> (E,C,D) bf16 ----------------
__global__ __launch_bounds__(256) void dispatch_kernel(
    const float* __restrict__ hidden, const int* __restrict__ exp_tok,
    const int* __restrict__ counts, unsigned short* __restrict__ disp)
{
    int s = blockIdx.x, e = blockIdx.y;
    unsigned short* dst = disp + ((size_t)e * CAP + s) * DIM + threadIdx.x * 8;
    if (s < counts[e]) {
        int n = exp_tok[e * CAP + s];
        const float* src = hidden + ((size_t)(n & 1) * SEQ + (n >> 1)) * DIM + threadIdx.x * 8;
        float4 a = *(const float4*)src;
        float4 b = *(const float4*)(src + 4);
        v8s o;
        o[0] = (short)f2b(a.x); o[1] = (short)f2b(a.y);
        o[2] = (short)f2b(a.z); o[3] = (short)f2b(a.w);
        o[4] = (short)f2b(b.x); o[5] = (short)f2b(b.y);
        o[6] = (short)f2b(b.z); o[7] = (short)f2b(b.w);
        *(v8s*)dst = o;
    } else {
        v8s z = {0, 0, 0, 0, 0, 0, 0, 0};
        *(v8s*)dst = z;
    }
}

// ---------------- GEMM tiling ----------------
// BM=256 x BN=128 tiles, BK=64.  Rationale vs the 128x128 round-2 version:
// B (fp32 weights) bytes per FLOP drop 0.6-0.67x (L2-side relief) and the
// per-K-step compute window doubles (~620 cyc) so the depth-1 prefetch
// covers more of the ~900-cyc HBM latency. Same proven 2-barrier pipeline:
// loads for tile k+1 issued right after the pre-compute barrier of tile k.
// A-tiles: async global_load_lds, double-buffered, XOR col-block swizzle via
// pre-swizzled GLOBAL source (LDS linear). B-tiles: reg-staged fp32 -> bf16.
#define BK 64

// stage one (NW*8*ROUNDS) x 64 bf16 tile into LDS.  NW = waves/block.
template<int NW, int ROUNDS>
__device__ __forceinline__ void stage_a(
    const unsigned short* __restrict__ gbase, int grow0, int k0, int rs,
    unsigned short* lds, int wv, int ln)
{
    int sr = ln >> 3;    // 0..7
    int cb = ln & 7;     // col-block
    #pragma unroll
    for (int p = 0; p < ROUNDS; ++p) {
        int r = p * (NW * 8) + wv * 8 + sr;
        const unsigned short* g = gbase + (size_t)(grow0 + r) * rs + k0 + ((cb ^ (r & 7)) << 3);
        async16(g, lds + (p * (NW * 8) + wv * 8) * 64);   // wave-uniform base
    }
}

// issue fp32 loads for one 128x64 tile into registers; NT threads/block.
// ROUNDS = 128 / (NT/8).  regs holds 2*ROUNDS float4.
template<int NT, int ROUNDS>
__device__ __forceinline__ void issue_bx(
    const float* __restrict__ gbase, int grow0, int k0, int rs,
    float4* regs, int tid)
{
    int cb = tid & 7;
    int r0 = tid >> 3;
    #pragma unroll
    for (int p = 0; p < ROUNDS; ++p) {
        const float* g = gbase + (size_t)(grow0 + p * (NT / 8) + r0) * rs + k0 + (cb << 3);
        regs[2 * p]     = *(const float4*)g;
        regs[2 * p + 1] = *(const float4*)(g + 4);
    }
}

// convert staged fp32 regs -> bf16, write to XOR-swizzled LDS slots
template<int NT, int ROUNDS>
__device__ __forceinline__ void write_bx(
    const float4* regs, unsigned short* lds, int tid)
{
    int cb = tid & 7;
    int r0 = tid >> 3;
    #pragma unroll
    for (int p = 0; p < ROUNDS; ++p) {
        int r = p * (NT / 8) + r0;
        float4 x = regs[2 * p], y = regs[2 * p + 1];
        v8s o;
        o[0] = (short)f2b(x.x); o[1] = (short)f2b(x.y);
        o[2] = (short)f2b(x.z); o[3] = (short)f2b(x.w);
        o[4] = (short)f2b(y.x); o[5] = (short)f2b(y.y);
        o[6] = (short)f2b(y.z); o[7] = (short)f2b(y.w);
        *(v8s*)&lds[r * 64 + ((cb ^ (r & 7)) << 3)] = o;
    }
}

// XCD-chunked bijective swizzle: 768 blocks = 8 XCDs x 96.
// Within a chunk mi varies fastest (3 m-blocks share a B panel on one XCD's
// L2), then ni, then e (2 experts per XCD).
__device__ __forceinline__ void grid_decomp3(int bid, int& mi, int& ni, int& e) {
    int swz = (bid & 7) * 96 + (bid >> 3);
    mi = swz % 3;
    int t = swz / 3;      // 0..255
    ni = t & 15;
    e  = t >> 4;
}

// Kernel 4: h = silu(disp @ gp^T) * (disp @ up^T), per expert. Out bf16 (E,C,I)
// 512 threads, 8 waves as 4(M) x 2(N); per-wave output 64x64 per gemm.
// LDS 96 KB dynamic: As[2] 32KB each? no: As 256x64 bf16 = 32KB, x2 buf = 64KB; Bg,Bu 16KB.
__global__ __launch_bounds__(512, 2) void gateup_kernel(
    const unsigned short* __restrict__ disp, const float* __restrict__ gp,
    const float* __restrict__ up, const int* __restrict__ counts,
    unsigned short* __restrict__ hbuf)
{
    extern __shared__ unsigned short smem[];
    unsigned short* As0 = smem;              // 16384 shorts (256x64)
    unsigned short* As1 = smem + 16384;
    unsigned short* Bgs = smem + 32768;      // 8192 shorts (128x64)
    unsigned short* Bus = smem + 40960;
    int mi, ni, e;
    grid_decomp3(blockIdx.x, mi, ni, e);
    int m0 = mi * 256;
    if (m0 >= counts[e]) return;   // rows beyond count never read by combine
    int n0 = ni * 128;
    int tid = threadIdx.x;
    int wv = tid >> 6, ln = tid & 63;
    int wm = wv >> 1, wn = wv & 1;          // 4 x 2 wave grid
    int lrow = ln & 15, quad = ln >> 4;
    int sw = lrow & 7;

    const unsigned short* Ab = disp + (size_t)e * CAP * DIM;
    const float* Gb = gp + (size_t)e * IDIM * DIM;
    const float* Ub = up + (size_t)e * IDIM * DIM;

    int arow[4], brow[4];
    #pragma unroll
    for (int i = 0; i < 4; ++i) {
        arow[i] = (wm * 64 + i * 16 + lrow) * 64;
        brow[i] = (wn * 64 + i * 16 + lrow) * 64;
    }

    v4f accg[4][4], accu[4][4];
    #pragma unroll
    for (int i = 0; i < 4; ++i)
        #pragma unroll
        for (int j = 0; j < 4; ++j) { accg[i][j] = (v4f)0.f; accu[i][j] = (v4f)0.f; }

    float4 rg[4], ru[4];
    // prologue: tile 0 in flight
    stage_a<8, 4>(Ab, m0, 0, DIM, As0, wv, ln);
    issue_bx<512, 2>(Gb, n0, 0, DIM, rg, tid);
    issue_bx<512, 2>(Ub, n0, 0, DIM, ru, tid);

    for (int k0 = 0; k0 < DIM; k0 += BK) {
        int cur = (k0 >> 6) & 1;
        unsigned short* Ac = cur ? As1 : As0;   // compute buffer
        unsigned short* An = cur ? As0 : As1;   // stage target
        __syncthreads();              // post-compute(k-1): drains in-flight tile k
        write_bx<512, 2>(rg, Bgs, tid);
        write_bx<512, 2>(ru, Bus, tid);
        __syncthreads();              // LDS visible to all waves
        int kn = k0 + BK;
        if (kn < DIM) {               // issue tile k+1: in flight during compute
            stage_a<8, 4>(Ab, m0, kn, DIM, An, wv, ln);
            issue_bx<512, 2>(Gb, n0, kn, DIM, rg, tid);
            issue_bx<512, 2>(Ub, n0, kn, DIM, ru, tid);
        }
        #pragma unroll
        for (int ks = 0; ks < BK; ks += 32) {
            int cq = ks >> 3;
            v8s a[4];
            #pragma unroll
            for (int i = 0; i < 4; ++i)
                a[i] = *(const v8s*)&Ac[arow[i] + (((cq + quad) ^ sw) << 3)];
            #pragma unroll
            for (int j = 0; j < 4; ++j) {
                v8s bg = *(const v8s*)&Bgs[brow[j] + (((cq + quad) ^ sw) << 3)];
                v8s bu = *(const v8s*)&Bus[brow[j] + (((cq + quad) ^ sw) << 3)];
                #pragma unroll
                for (int i = 0; i < 4; ++i) {
                    accg[i][j] = __builtin_amdgcn_mfma_f32_16x16x32_bf16(a[i], bg, accg[i][j], 0, 0, 0);
                    accu[i][j] = __builtin_amdgcn_mfma_f32_16x16x32_bf16(a[i], bu, accu[i][j], 0, 0, 0);
                }
            }
        }
    }
    unsigned short* hb = hbuf + (size_t)e * CAP * IDIM;
    #pragma unroll
    for (int i = 0; i < 4; ++i)
        #pragma unroll
        for (int j = 0; j < 4; ++j) {
            int row = m0 + wm * 64 + i * 16 + quad * 4;
            int col = n0 + wn * 64 + j * 16 + lrow;
            #pragma unroll
            for (int rg_ = 0; rg_ < 4; ++rg_) {
                if (row + rg_ < CAP) {      // m0=512 block computes rows up to 767
                    float g = accg[i][j][rg_], u = accu[i][j][rg_];
                    float hv = (g / (1.f + __expf(-g))) * u;
                    hb[(size_t)(row + rg_) * IDIM + col] = f2b(hv);
                }
            }
        }
}

// Kernel 5: expert_out = h @ dp^T per expert. Out bf16 (E,C,D)
// 256 threads, 4 waves as 2(M) x 2(N); per-wave output 128x64.
// LDS 80 KB dynamic: As 2x32KB + Bs 16KB -> 2 blocks/CU.
__global__ __launch_bounds__(256, 2) void down_kernel(
    const unsigned short* __restrict__ hbuf, const float* __restrict__ dp,
    const int* __restrict__ counts, unsigned short* __restrict__ eo)
{
    extern __shared__ unsigned short smem[];
    unsigned short* As0 = smem;
    unsigned short* As1 = smem + 16384;
    unsigned short* Bs  = smem + 32768;      // 8192 shorts
    int mi, ni, e;
    grid_decomp3(blockIdx.x, mi, ni, e);
    int m0 = mi * 256;
    if (m0 >= counts[e]) return;
    int n0 = ni * 128;
    int tid = threadIdx.x;
    int wv = tid >> 6, ln = tid & 63;
    int wm = wv >> 1, wn = wv & 1;          // 2 x 2 wave grid
    int lrow = ln & 15, quad = ln >> 4;
    int sw = lrow & 7;

    const unsigned short* Ab = hbuf + (size_t)e * CAP * IDIM;
    const float* Db = dp + (size_t)e * DIM * IDIM;

    int arow[8], brow[4];
    #pragma unroll
    for (int i = 0; i < 8; ++i)
        arow[i] = (wm * 128 + i * 16 + lrow) * 64;
    #pragma unroll
    for (int j = 0; j < 4; ++j)
        brow[j] = (wn * 64 + j * 16 + lrow) * 64;

    v4f acc[8][4];
    #pragma unroll
    for (int i = 0; i < 8; ++i)
        #pragma unroll
        for (int j = 0; j < 4; ++j) acc[i][j] = (v4f)0.f;

    float4 rb[8];
    stage_a<4, 8>(Ab, m0, 0, IDIM, As0, wv, ln);
    issue_bx<256, 4>(Db, n0, 0, IDIM, rb, tid);

    for (int k0 = 0; k0 < IDIM; k0 += BK) {
        int cur = (k0 >> 6) & 1;
        unsigned short* Ac = cur ? As1 : As0;
        unsigned short* An = cur ? As0 : As1;
        __syncthreads();
        write_bx<256, 4>(rb, Bs, tid);
        __syncthreads();
        int kn = k0 + BK;
        if (kn < IDIM) {
            stage_a<4, 8>(Ab, m0, kn, IDIM, An, wv, ln);
            issue_bx<256, 4>(Db, n0, kn, IDIM, rb, tid);
        }
        #pragma unroll
        for (int ks = 0; ks < BK; ks += 32) {
            int cq = ks >> 3;
            v8s a[8];
            #pragma unroll
            for (int i = 0; i < 8; ++i)
                a[i] = *(const v8s*)&Ac[arow[i] + (((cq + quad) ^ sw) << 3)];
            #pragma unroll
            for (int j = 0; j < 4; ++j) {
                v8s b = *(const v8s*)&Bs[brow[j] + (((cq + quad) ^ sw) << 3)];
                #pragma unroll
                for (int i = 0; i < 8; ++i)
                    acc[i][j] = __builtin_amdgcn_mfma_f32_16x16x32_bf16(a[i], b, acc[i][j], 0, 0, 0);
            }
        }
    }
    unsigned short* ob = eo + (size_t)e * CAP * DIM;
    #pragma unroll
    for (int i = 0; i < 8; ++i)
        #pragma unroll
        for (int j = 0; j < 4; ++j) {
            int row = m0 + wm * 128 + i * 16 + quad * 4;
            int col = n0 + wn * 64 + j * 16 + lrow;
            #pragma unroll
            for (int rg_ = 0; rg_ < 4; ++rg_) {
                if (row + rg_ < CAP)
                    ob[(size_t)(row + rg_) * DIM + col] = f2b(acc[i][j][rg_]);
            }
        }
}

// ---------------- Kernel 6: combine ----------------
__global__ __launch_bounds__(256) void combine_kernel(
    const unsigned short* __restrict__ eo,
    const int* __restrict__ top1, const int* __restrict__ top2,
    const int* __restrict__ slot1, const int* __restrict__ slot2,
    const float* __restrict__ w1, const float* __restrict__ w2,
    float* __restrict__ out)
{
    int n = blockIdx.x;
    int d = threadIdx.x * 8;
    float acc[8];
    #pragma unroll
    for (int i = 0; i < 8; ++i) acc[i] = 0.f;
    int s1 = slot1[n], s2 = slot2[n];
    if (s1 < CAP) {
        const unsigned short* p = eo + ((size_t)top1[n] * CAP + s1) * DIM + d;
        float w = w1[n];
        v8s v = *(const v8s*)p;
        #pragma unroll
        for (int i = 0; i < 8; ++i) acc[i] += w * b2f((unsigned short)v[i]);
    }
    if (s2 < CAP) {
        const unsigned short* p = eo + ((size_t)top2[n] * CAP + s2) * DIM + d;
        float w = w2[n];
        v8s v = *(const v8s*)p;
        #pragma unroll
        for (int i = 0; i < 8; ++i) acc[i] += w * b2f((unsigned short)v[i]);
    }
    float* o = out + ((size_t)(n & 1) * SEQ + (n >> 1)) * DIM + d;
    float4 o0 = {acc[0], acc[1], acc[2], acc[3]};
    float4 o1 = {acc[4], acc[5], acc[6], acc[7]};
    *(float4*)o = o0;
    *(float4*)(o + 4) = o1;
}

extern "C" void kernel_launch(void* const* d_in, const int* in_sizes, int n_in,
                              void* d_out, int out_size, void* d_ws, size_t ws_size,
                              hipStream_t stream) {
    const float* hidden = (const float*)d_in[0];
    const float* wg     = (const float*)d_in[1];
    const float* gp     = (const float*)d_in[2];
    const float* up     = (const float*)d_in[3];
    const float* dp     = (const float*)d_in[4];
    float* out = (float*)d_out;
    char* ws = (char*)d_ws;

    // workspace layout
    int*   top1    = (int*)(ws + 0);
    int*   top2    = (int*)(ws + 16384);
    float* w1      = (float*)(ws + 32768);
    float* w2      = (float*)(ws + 49152);
    int*   slot1   = (int*)(ws + 65536);
    int*   slot2   = (int*)(ws + 81920);
    int*   counts  = (int*)(ws + 98304);
    int*   exp_tok = (int*)(ws + 98560);
    unsigned short* disp = (unsigned short*)(ws + 262144);                    // 41,943,040 B
    unsigned short* hbuf = (unsigned short*)(ws + 262144 + 41943040ull);      // 41,943,040 B
    unsigned short* eo   = (unsigned short*)(ws + 262144 + 2ull*41943040ull); // 41,943,040 B
    // total ~126 MB

    static bool attr_set = false;
    if (!attr_set) {
        hipFuncSetAttribute((const void*)gateup_kernel,
                            hipFuncAttributeMaxDynamicSharedMemorySize, 98304);
        hipFuncSetAttribute((const void*)down_kernel,
                            hipFuncAttributeMaxDynamicSharedMemorySize, 81920);
        attr_set = true;
    }

    const int NB = 3 * 16 * NEXP;   // 768, = 8 XCDs * 96

    router_kernel<<<NTOK / 4, 256, 0, stream>>>(hidden, wg, top1, top2, w1, w2);
    slot_kernel<<<1, 1024, 0, stream>>>(top1, top2, slot1, slot2, exp_tok, counts);
    dispatch_kernel<<<dim3(CAP, NEXP), 256, 0, stream>>>(hidden, exp_tok, counts, disp);
    gateup_kernel<<<NB, 512, 98304, stream>>>(disp, gp, up, counts, hbuf);
    down_kernel<<<NB, 256, 81920, stream>>>(hbuf, dp, counts, eo);
    combine_kernel<<<NTOK, 256, 0, stream>>>(eo, top1, top2, slot1, slot2, w1, w2, out);
}